// Round 1
// baseline (21745.825 us; speedup 1.0000x reference)
//
#include <hip/hip_runtime.h>
#include <math.h>

#define NNODES 50000
#define NEDGES 1600000

__device__ __forceinline__ float lrelu(float v) { return v > 0.f ? v : 0.2f * v; }

// h[n][c] = sum_k X[n][k] * W[k][c]   (W staged in LDS)
template<int DIN, int C>
__global__ void gemm_kernel(const float* __restrict__ X, const float* __restrict__ W,
                            float* __restrict__ Out, int N) {
    __shared__ float Wl[DIN * C];
    for (int i = threadIdx.x; i < DIN * C; i += blockDim.x) Wl[i] = W[i];
    __syncthreads();
    int t = blockIdx.x * blockDim.x + threadIdx.x;
    if (t >= N * C) return;
    int n = t / C, c = t - n * C;
    const float* xr = X + (size_t)n * DIN;
    float acc = 0.f;
#pragma unroll
    for (int k = 0; k < DIN; ++k) acc = fmaf(xr[k], Wl[k * C + c], acc);
    Out[t] = acc;
}

// alpha_s[n][h] = <h[n,h,:], a_s[h,:]>, same for alpha_d
template<int H, int F>
__global__ void alpha_kernel(const float* __restrict__ Hin, const float* __restrict__ As,
                             const float* __restrict__ Ad, float* __restrict__ as_o,
                             float* __restrict__ ad_o, int N) {
    int t = blockIdx.x * blockDim.x + threadIdx.x;
    if (t >= N * H) return;
    int n = t / H, hh = t - n * H;
    const float* hr = Hin + (size_t)n * (H * F) + hh * F;
    float s = 0.f, d = 0.f;
#pragma unroll
    for (int f = 0; f < F; ++f) {
        float v = hr[f];
        s = fmaf(v, As[hh * F + f], s);
        d = fmaf(v, Ad[hh * F + f], d);
    }
    as_o[t] = s;
    ad_o[t] = d;
}

// denom[dst][h] += exp(leaky_relu(alpha_s[src][h] + alpha_d[dst][h]))
template<int H>
__global__ void edge_denom_kernel(const int* __restrict__ src, const int* __restrict__ dst,
                                  const float* __restrict__ as_, const float* __restrict__ ad_,
                                  float* __restrict__ denom, int E) {
    int t = blockIdx.x * blockDim.x + threadIdx.x;
    if (t >= E * H) return;
    int e = t / H, hh = t - e * H;
    int s = src[e], d = dst[e];
    float v = lrelu(as_[s * H + hh] + ad_[d * H + hh]);
    atomicAdd(&denom[d * H + hh], __expf(v));
}

// agg[dst][h*F+f] += h[src][h*F+f] * att(e,h)
template<int H, int F>
__global__ void msg_kernel(const int* __restrict__ src, const int* __restrict__ dst,
                           const float* __restrict__ as_, const float* __restrict__ ad_,
                           const float* __restrict__ denom, const float* __restrict__ Hin,
                           float* __restrict__ agg, int E) {
    constexpr int C = H * F;
    int t = blockIdx.x * blockDim.x + threadIdx.x;
    if (t >= E * H) return;
    int e = t / H, hh = t - e * H;
    int s = src[e], d = dst[e];
    float v = lrelu(as_[s * H + hh] + ad_[d * H + hh]);
    float att = __expf(v) / (denom[d * H + hh] + 1e-12f);
    const float4* hr = (const float4*)(Hin + (size_t)s * C + hh * F);
    float* ar = agg + (size_t)d * C + hh * F;
#pragma unroll
    for (int q = 0; q < F / 4; ++q) {
        float4 hv = hr[q];
        atomicAdd(ar + 4 * q + 0, hv.x * att);
        atomicAdd(ar + 4 * q + 1, hv.y * att);
        atomicAdd(ar + 4 * q + 2, hv.z * att);
        atomicAdd(ar + 4 * q + 3, hv.w * att);
    }
}

__global__ void elu_kernel(float* __restrict__ a, int n) {
    int t = blockIdx.x * blockDim.x + threadIdx.x;
    if (t >= n) return;
    float v = a[t];
    a[t] = v > 0.f ? v : expm1f(v);
}

// pooled[c] = sum_n a[n][c]   (block-local LDS accumulation, then one atomic per col)
__global__ void pool_kernel(const float* __restrict__ a, float* __restrict__ pooled, int total) {
    __shared__ float sp[144];
    for (int i = threadIdx.x; i < 144; i += blockDim.x) sp[i] = 0.f;
    __syncthreads();
    for (int t = blockIdx.x * blockDim.x + threadIdx.x; t < total; t += gridDim.x * blockDim.x) {
        atomicAdd(&sp[t % 144], a[t]);
    }
    __syncthreads();
    for (int i = threadIdx.x; i < 144; i += blockDim.x) atomicAdd(&pooled[i], sp[i]);
}

// out = dot(pooled, Wd) / max(||pooled||, 1e-12) + bd
__global__ void final_kernel(const float* __restrict__ pooled, const float* __restrict__ Wd,
                             const float* __restrict__ bd, float* __restrict__ out) {
    int l = threadIdx.x;
    float ss = 0.f, dot = 0.f;
    for (int c = l; c < 144; c += 64) {
        float p = pooled[c];
        ss = fmaf(p, p, ss);
        dot = fmaf(p, Wd[c], dot);
    }
#pragma unroll
    for (int o = 32; o > 0; o >>= 1) {
        ss += __shfl_down(ss, o);
        dot += __shfl_down(dot, o);
    }
    if (l == 0) out[0] = dot / fmaxf(sqrtf(ss), 1e-12f) + bd[0];
}

extern "C" void kernel_launch(void* const* d_in, const int* in_sizes, int n_in,
                              void* d_out, int out_size, void* d_ws, size_t ws_size,
                              hipStream_t stream) {
    const float* x   = (const float*)d_in[0];
    const int*   src = (const int*)  d_in[1];
    const int*   dst = (const int*)  d_in[2];
    const float* W1  = (const float*)d_in[3];
    const float* a1s = (const float*)d_in[4];
    const float* a1d = (const float*)d_in[5];
    const float* W2  = (const float*)d_in[6];
    const float* a2s = (const float*)d_in[7];
    const float* a2d = (const float*)d_in[8];
    const float* Wd  = (const float*)d_in[9];
    const float* bd  = (const float*)d_in[10];

    const int N = NNODES, E = NEDGES;
    float* ws = (float*)d_ws;
    // layout (floats); agg2 deliberately overlaps h1+agg1 (both dead by then)
    float* h1     = ws;                                   // N*96
    float* agg1   = ws + (size_t)N * 96;                  // N*96 (=out1 after elu)
    float* h2     = ws + (size_t)2 * N * 96;              // N*144
    float* as_    = h2 + (size_t)N * 144;                 // N*6
    float* ad_    = as_ + (size_t)N * 6;                  // N*6
    float* den    = ad_ + (size_t)N * 6;                  // N*6
    float* pooled = den + (size_t)N * 6;                  // 144
    float* agg2   = ws;                                   // N*144 (overlaps h1 + half of agg1)

    const int B = 256;
    auto grid = [](long total, int b) { return (int)((total + b - 1) / b); };

    // ---- layer 1 ----
    gemm_kernel<11, 96><<<grid((long)N * 96, B), B, 0, stream>>>(x, W1, h1, N);
    alpha_kernel<6, 16><<<grid((long)N * 6, B), B, 0, stream>>>(h1, a1s, a1d, as_, ad_, N);
    hipMemsetAsync(den, 0, (size_t)N * 6 * sizeof(float), stream);
    edge_denom_kernel<6><<<grid((long)E * 6, B), B, 0, stream>>>(src, dst, as_, ad_, den, E);
    hipMemsetAsync(agg1, 0, (size_t)N * 96 * sizeof(float), stream);
    msg_kernel<6, 16><<<grid((long)E * 6, B), B, 0, stream>>>(src, dst, as_, ad_, den, h1, agg1, E);
    elu_kernel<<<grid((long)N * 96, B), B, 0, stream>>>(agg1, N * 96);

    // ---- layer 2 ----
    gemm_kernel<96, 144><<<grid((long)N * 144, B), B, 0, stream>>>(agg1, W2, h2, N);
    alpha_kernel<6, 24><<<grid((long)N * 6, B), B, 0, stream>>>(h2, a2s, a2d, as_, ad_, N);
    hipMemsetAsync(den, 0, (size_t)N * 6 * sizeof(float), stream);
    edge_denom_kernel<6><<<grid((long)E * 6, B), B, 0, stream>>>(src, dst, as_, ad_, den, E);
    hipMemsetAsync(agg2, 0, (size_t)N * 144 * sizeof(float), stream);
    msg_kernel<6, 24><<<grid((long)E * 6, B), B, 0, stream>>>(src, dst, as_, ad_, den, h2, agg2, E);
    elu_kernel<<<grid((long)N * 144, B), B, 0, stream>>>(agg2, N * 144);

    // ---- pool + normalize + linear ----
    hipMemsetAsync(pooled, 0, 144 * sizeof(float), stream);
    pool_kernel<<<1024, 256, 0, stream>>>(agg2, pooled, N * 144);
    final_kernel<<<1, 64, 0, stream>>>(pooled, Wd, bd, (float*)d_out);
}

// Round 2
// 1426.355 us; speedup vs baseline: 15.2457x; 15.2457x over previous
//
#include <hip/hip_runtime.h>
#include <math.h>

#define NNODES 50000
#define NEDGES 1600000

__device__ __forceinline__ float lrelu(float v) { return v > 0.f ? v : 0.2f * v; }

// h[n][c] = sum_k X[n][k] * W[k][c]   (W staged in LDS)
template<int DIN, int C>
__global__ void gemm_kernel(const float* __restrict__ X, const float* __restrict__ W,
                            float* __restrict__ Out, int N) {
    __shared__ float Wl[DIN * C];
    for (int i = threadIdx.x; i < DIN * C; i += blockDim.x) Wl[i] = W[i];
    __syncthreads();
    int t = blockIdx.x * blockDim.x + threadIdx.x;
    if (t >= N * C) return;
    int n = t / C, c = t - n * C;
    const float* xr = X + (size_t)n * DIN;
    float acc = 0.f;
#pragma unroll
    for (int k = 0; k < DIN; ++k) acc = fmaf(xr[k], Wl[k * C + c], acc);
    Out[t] = acc;
}

// alpha_s[n][h] = <h[n,h,:], a_s[h,:]>, same for alpha_d
template<int H, int F>
__global__ void alpha_kernel(const float* __restrict__ Hin, const float* __restrict__ As,
                             const float* __restrict__ Ad, float* __restrict__ as_o,
                             float* __restrict__ ad_o, int N) {
    int t = blockIdx.x * blockDim.x + threadIdx.x;
    if (t >= N * H) return;
    int n = t / H, hh = t - n * H;
    const float* hr = Hin + (size_t)n * (H * F) + hh * F;
    float s = 0.f, d = 0.f;
#pragma unroll
    for (int f = 0; f < F; ++f) {
        float v = hr[f];
        s = fmaf(v, As[hh * F + f], s);
        d = fmaf(v, Ad[hh * F + f], d);
    }
    as_o[t] = s;
    ad_o[t] = d;
}

// ---- CSR build (dst-indexed; shared by both layers) ----
__global__ void hist_kernel(const int* __restrict__ dst, int* __restrict__ cnt, int E) {
    int t = blockIdx.x * blockDim.x + threadIdx.x;
    if (t < E) atomicAdd(&cnt[dst[t]], 1);
}

// single block, 1024 threads: exclusive scan of cnt[N] -> off[N+1]; cnt becomes cursor copy
__global__ void scan_kernel(int* __restrict__ cnt, int* __restrict__ off, int N) {
    __shared__ int ls[1024];
    int t = threadIdx.x;
    const int CH = (N + 1023) / 1024;
    int base = t * CH, lim = min(base + CH, N);
    int s = 0;
    for (int i = base; i < lim; ++i) s += cnt[i];
    ls[t] = s;
    __syncthreads();
    for (int o = 1; o < 1024; o <<= 1) {
        int u = (t >= o) ? ls[t - o] : 0;
        __syncthreads();
        ls[t] += u;
        __syncthreads();
    }
    int run = ls[t] - s;  // exclusive prefix for this chunk
    for (int i = base; i < lim; ++i) { int c = cnt[i]; off[i] = run; run += c; }
    if (t == 1023) off[N] = ls[1023];
    __syncthreads();
    for (int i = base; i < lim; ++i) cnt[i] = off[i];  // cursor init
}

__global__ void scatter_kernel(const int* __restrict__ src, const int* __restrict__ dst,
                               int* __restrict__ cur, int* __restrict__ esrc, int E) {
    int t = blockIdx.x * blockDim.x + threadIdx.x;
    if (t >= E) return;
    int pos = atomicAdd(&cur[dst[t]], 1);
    esrc[pos] = src[t];
}

// rden[n][h] = 1 / (sum_{e into n} exp(lrelu(as[src]+ad[n])) + eps)
template<int H>
__global__ void denom_kernel(const int* __restrict__ off, const int* __restrict__ esrc,
                             const float* __restrict__ as_, const float* __restrict__ ad_,
                             float* __restrict__ rden, int N) {
    int t = blockIdx.x * blockDim.x + threadIdx.x;
    if (t >= N * H) return;
    int n = t / H;
    int h = t - n * H;
    float adv = ad_[t];
    int p0 = off[n], p1 = off[n + 1];
    float den = 0.f;
    for (int p = p0; p < p1; ++p) {
        int s = esrc[p];
        den += __expf(lrelu(as_[s * H + h] + adv));
    }
    rden[t] = 1.f / (den + 1e-12f);
}

// out[n][c] = elu( rden[n][h] * sum_e exp(lrelu(as[s]+ad[n])) * Hin[s][c] )
template<int H, int F>
__global__ void gather_kernel(const int* __restrict__ off, const int* __restrict__ esrc,
                              const float* __restrict__ as_, const float* __restrict__ ad_,
                              const float* __restrict__ rden, const float* __restrict__ Hin,
                              float* __restrict__ out, int N) {
    constexpr int C = H * F;
    int t = blockIdx.x * blockDim.x + threadIdx.x;
    if (t >= N * C) return;
    int n = t / C, c = t - n * C;
    int h = c / F;
    float adv = ad_[n * H + h];
    float rd = rden[n * H + h];
    int p0 = off[n], p1 = off[n + 1];
    float acc = 0.f;
    for (int p = p0; p < p1; ++p) {
        int s = esrc[p];
        float att = __expf(lrelu(as_[s * H + h] + adv));
        acc = fmaf(att, Hin[(size_t)s * C + c], acc);
    }
    float r = acc * rd;
    out[t] = r > 0.f ? r : expm1f(r);
}

// pooled[c] = sum_n a[n][c]
__global__ void pool_kernel(const float* __restrict__ a, float* __restrict__ pooled, int total) {
    __shared__ float sp[144];
    for (int i = threadIdx.x; i < 144; i += blockDim.x) sp[i] = 0.f;
    __syncthreads();
    for (int t = blockIdx.x * blockDim.x + threadIdx.x; t < total; t += gridDim.x * blockDim.x) {
        atomicAdd(&sp[t % 144], a[t]);
    }
    __syncthreads();
    for (int i = threadIdx.x; i < 144; i += blockDim.x) atomicAdd(&pooled[i], sp[i]);
}

// out = dot(pooled, Wd) / max(||pooled||, 1e-12) + bd
__global__ void final_kernel(const float* __restrict__ pooled, const float* __restrict__ Wd,
                             const float* __restrict__ bd, float* __restrict__ out) {
    int l = threadIdx.x;
    float ss = 0.f, dot = 0.f;
    for (int c = l; c < 144; c += 64) {
        float p = pooled[c];
        ss = fmaf(p, p, ss);
        dot = fmaf(p, Wd[c], dot);
    }
#pragma unroll
    for (int o = 32; o > 0; o >>= 1) {
        ss += __shfl_down(ss, o);
        dot += __shfl_down(dot, o);
    }
    if (l == 0) out[0] = dot / fmaxf(sqrtf(ss), 1e-12f) + bd[0];
}

extern "C" void kernel_launch(void* const* d_in, const int* in_sizes, int n_in,
                              void* d_out, int out_size, void* d_ws, size_t ws_size,
                              hipStream_t stream) {
    const float* x   = (const float*)d_in[0];
    const int*   src = (const int*)  d_in[1];
    const int*   dst = (const int*)  d_in[2];
    const float* W1  = (const float*)d_in[3];
    const float* a1s = (const float*)d_in[4];
    const float* a1d = (const float*)d_in[5];
    const float* W2  = (const float*)d_in[6];
    const float* a2s = (const float*)d_in[7];
    const float* a2d = (const float*)d_in[8];
    const float* Wd  = (const float*)d_in[9];
    const float* bd  = (const float*)d_in[10];

    const int N = NNODES, E = NEDGES;
    float* ws = (float*)d_ws;
    // Region A/B ping-pong (each N*144 floats):
    //  L1: h1 -> A, agg1 -> B.  L2: h2 -> A (h1 dead), agg2 -> B (agg1 dead after gemm).
    float* regA   = ws;                                   // N*144
    float* regB   = ws + (size_t)N * 144;                 // N*144
    float* as_    = ws + (size_t)2 * N * 144;             // N*6
    float* ad_    = as_ + (size_t)N * 6;                  // N*6
    float* rden   = ad_ + (size_t)N * 6;                  // N*6
    float* pooled = rden + (size_t)N * 6;                 // 144
    int*   off    = (int*)(pooled + 144);                 // N+1
    int*   cur    = off + (N + 1);                        // N (also histogram counts)
    int*   esrc   = cur + N;                              // E

    const int B = 256;
    auto grid = [](long total, int b) { return (int)((total + b - 1) / b); };

    // ---- CSR build (dst shared by both layers) ----
    hipMemsetAsync(cur, 0, (size_t)N * sizeof(int), stream);
    hist_kernel<<<grid(E, B), B, 0, stream>>>(dst, cur, E);
    scan_kernel<<<1, 1024, 0, stream>>>(cur, off, N);
    scatter_kernel<<<grid(E, B), B, 0, stream>>>(src, dst, cur, esrc, E);

    // ---- layer 1 ----
    gemm_kernel<11, 96><<<grid((long)N * 96, B), B, 0, stream>>>(x, W1, regA, N);
    alpha_kernel<6, 16><<<grid((long)N * 6, B), B, 0, stream>>>(regA, a1s, a1d, as_, ad_, N);
    denom_kernel<6><<<grid((long)N * 6, B), B, 0, stream>>>(off, esrc, as_, ad_, rden, N);
    gather_kernel<6, 16><<<grid((long)N * 96, B), B, 0, stream>>>(off, esrc, as_, ad_, rden, regA, regB, N);

    // ---- layer 2 ----
    gemm_kernel<96, 144><<<grid((long)N * 144, B), B, 0, stream>>>(regB, W2, regA, N);
    alpha_kernel<6, 24><<<grid((long)N * 6, B), B, 0, stream>>>(regA, a2s, a2d, as_, ad_, N);
    denom_kernel<6><<<grid((long)N * 6, B), B, 0, stream>>>(off, esrc, as_, ad_, rden, N);
    gather_kernel<6, 24><<<grid((long)N * 144, B), B, 0, stream>>>(off, esrc, as_, ad_, rden, regA, regB, N);

    // ---- pool + normalize + linear ----
    hipMemsetAsync(pooled, 0, 144 * sizeof(float), stream);
    pool_kernel<<<1024, 256, 0, stream>>>(regB, pooled, N * 144);
    final_kernel<<<1, 64, 0, stream>>>(pooled, Wd, bd, (float*)d_out);
}

// Round 3
// 681.130 us; speedup vs baseline: 31.9261x; 2.0941x over previous
//
#include <hip/hip_runtime.h>
#include <math.h>

#define NNODES 50000
#define NEDGES 1600000

__device__ __forceinline__ float lrelu(float v) { return v > 0.f ? v : 0.2f * v; }

// Out[n][c] = sum_k X[n][k] * W[k][c], thread = (node pair, float4 col quad)
template<int DIN, int C, int NPT>
__global__ void gemm4_kernel(const float* __restrict__ X, const float* __restrict__ W,
                             float* __restrict__ Out, int N) {
    constexpr int Q = C / 4;
    __shared__ float4 Wl[DIN * Q];
    for (int i = threadIdx.x; i < DIN * Q; i += blockDim.x)
        Wl[i] = ((const float4*)W)[i];
    __syncthreads();
    int t = blockIdx.x * blockDim.x + threadIdx.x;
    int g = t / Q, q = t - g * Q;
    int n0 = g * NPT;
    if (n0 >= N) return;
    const float* xr = X + (size_t)n0 * DIN;
    float4 acc[NPT];
#pragma unroll
    for (int u = 0; u < NPT; ++u) acc[u] = make_float4(0.f, 0.f, 0.f, 0.f);
#pragma unroll 4
    for (int k = 0; k < DIN; ++k) {
        float4 w = Wl[k * Q + q];
#pragma unroll
        for (int u = 0; u < NPT; ++u) {
            float xv = xr[(size_t)u * DIN + k];
            acc[u].x = fmaf(xv, w.x, acc[u].x);
            acc[u].y = fmaf(xv, w.y, acc[u].y);
            acc[u].z = fmaf(xv, w.z, acc[u].z);
            acc[u].w = fmaf(xv, w.w, acc[u].w);
        }
    }
#pragma unroll
    for (int u = 0; u < NPT; ++u)
        ((float4*)Out)[(size_t)(n0 + u) * Q + q] = acc[u];
}

// alpha_s[n][h] = <h[n,h,:], a_s[h,:]>, same for alpha_d
template<int H, int F>
__global__ void alpha_kernel(const float* __restrict__ Hin, const float* __restrict__ As,
                             const float* __restrict__ Ad, float* __restrict__ as_o,
                             float* __restrict__ ad_o, int N) {
    int t = blockIdx.x * blockDim.x + threadIdx.x;
    if (t >= N * H) return;
    int n = t / H, hh = t - n * H;
    const float* hr = Hin + (size_t)n * (H * F) + hh * F;
    float s = 0.f, d = 0.f;
#pragma unroll
    for (int f = 0; f < F; ++f) {
        float v = hr[f];
        s = fmaf(v, As[hh * F + f], s);
        d = fmaf(v, Ad[hh * F + f], d);
    }
    as_o[t] = s;
    ad_o[t] = d;
}

// ---- CSR build (dst-indexed; shared by both layers) ----
__global__ void hist_kernel(const int* __restrict__ dst, int* __restrict__ cnt, int E) {
    int t = blockIdx.x * blockDim.x + threadIdx.x;
    if (t < E) atomicAdd(&cnt[dst[t]], 1);
}

// single block, 1024 threads: exclusive scan of cnt[N] -> off[N+1]; cnt becomes cursor copy
__global__ void scan_kernel(int* __restrict__ cnt, int* __restrict__ off, int N) {
    __shared__ int ls[1024];
    int t = threadIdx.x;
    const int CH = (N + 1023) / 1024;
    int base = t * CH, lim = min(base + CH, N);
    int s = 0;
    for (int i = base; i < lim; ++i) s += cnt[i];
    ls[t] = s;
    __syncthreads();
    for (int o = 1; o < 1024; o <<= 1) {
        int u = (t >= o) ? ls[t - o] : 0;
        __syncthreads();
        ls[t] += u;
        __syncthreads();
    }
    int run = ls[t] - s;  // exclusive prefix for this chunk
    for (int i = base; i < lim; ++i) { int c = cnt[i]; off[i] = run; run += c; }
    if (t == 1023) off[N] = ls[1023];
    __syncthreads();
    for (int i = base; i < lim; ++i) cnt[i] = off[i];  // cursor init
}

__global__ void scatter_kernel(const int* __restrict__ src, const int* __restrict__ dst,
                               int* __restrict__ cur, int* __restrict__ esrc, int E) {
    int t = blockIdx.x * blockDim.x + threadIdx.x;
    if (t >= E) return;
    int pos = atomicAdd(&cur[dst[t]], 1);
    esrc[pos] = src[t];
}

// Fused denom + gather + elu:
// out[n][c4] = elu( (sum_e att_e * Hin[s][c4]) / (sum_e att_e + eps) ),
// att_e = exp(lrelu(as[s][h] + ad[n][h])).  Thread = (node, float4 quad).
template<int H, int F>
__global__ void gather_kernel(const int* __restrict__ off, const int* __restrict__ esrc,
                              const float* __restrict__ as_, const float* __restrict__ ad_,
                              const float* __restrict__ Hin, float* __restrict__ out, int N) {
    constexpr int C = H * F;
    constexpr int Q = C / 4;
    int t = blockIdx.x * blockDim.x + threadIdx.x;
    if (t >= N * Q) return;
    int n = t / Q, q = t - n * Q;
    int h = q / (F / 4);
    float adv = ad_[n * H + h];
    int p0 = off[n], p1 = off[n + 1];
    const float4* Hin4 = (const float4*)Hin;
    float4 acc = make_float4(0.f, 0.f, 0.f, 0.f);
    float den = 0.f;
    for (int p = p0; p < p1; ++p) {
        int s = esrc[p];
        float att = __expf(lrelu(as_[s * H + h] + adv));
        den += att;
        float4 hv = Hin4[(size_t)s * Q + q];
        acc.x = fmaf(att, hv.x, acc.x);
        acc.y = fmaf(att, hv.y, acc.y);
        acc.z = fmaf(att, hv.z, acc.z);
        acc.w = fmaf(att, hv.w, acc.w);
    }
    float rd = 1.f / (den + 1e-12f);
    float4 r;
    r.x = acc.x * rd; r.y = acc.y * rd; r.z = acc.z * rd; r.w = acc.w * rd;
    r.x = r.x > 0.f ? r.x : expm1f(r.x);
    r.y = r.y > 0.f ? r.y : expm1f(r.y);
    r.z = r.z > 0.f ? r.z : expm1f(r.z);
    r.w = r.w > 0.f ? r.w : expm1f(r.w);
    ((float4*)out)[t] = r;
}

// pooled[c] = sum_n a[n][c]; launch with gridDim*blockDim == 144*R
__global__ void pool_kernel(const float* __restrict__ a, float* __restrict__ pooled, int Nn) {
    int tid = blockIdx.x * blockDim.x + threadIdx.x;
    int c = tid % 144;
    int r0 = tid / 144;
    int RS = (gridDim.x * blockDim.x) / 144;
    float acc = 0.f;
    for (int r = r0; r < Nn; r += RS)
        acc += a[(size_t)r * 144 + c];
    atomicAdd(&pooled[c], acc);
}

// out = dot(pooled, Wd) / max(||pooled||, 1e-12) + bd
__global__ void final_kernel(const float* __restrict__ pooled, const float* __restrict__ Wd,
                             const float* __restrict__ bd, float* __restrict__ out) {
    int l = threadIdx.x;
    float ss = 0.f, dot = 0.f;
    for (int c = l; c < 144; c += 64) {
        float p = pooled[c];
        ss = fmaf(p, p, ss);
        dot = fmaf(p, Wd[c], dot);
    }
#pragma unroll
    for (int o = 32; o > 0; o >>= 1) {
        ss += __shfl_down(ss, o);
        dot += __shfl_down(dot, o);
    }
    if (l == 0) out[0] = dot / fmaxf(sqrtf(ss), 1e-12f) + bd[0];
}

extern "C" void kernel_launch(void* const* d_in, const int* in_sizes, int n_in,
                              void* d_out, int out_size, void* d_ws, size_t ws_size,
                              hipStream_t stream) {
    const float* x   = (const float*)d_in[0];
    const int*   src = (const int*)  d_in[1];
    const int*   dst = (const int*)  d_in[2];
    const float* W1  = (const float*)d_in[3];
    const float* a1s = (const float*)d_in[4];
    const float* a1d = (const float*)d_in[5];
    const float* W2  = (const float*)d_in[6];
    const float* a2s = (const float*)d_in[7];
    const float* a2d = (const float*)d_in[8];
    const float* Wd  = (const float*)d_in[9];
    const float* bd  = (const float*)d_in[10];

    const int N = NNODES, E = NEDGES;
    float* ws = (float*)d_ws;
    // Region A/B ping-pong (each N*144 floats):
    //  L1: h1 -> A, agg1 -> B.  L2: h2 -> A (h1 dead), agg2 -> B (agg1 dead after gemm).
    float* regA   = ws;                                   // N*144
    float* regB   = ws + (size_t)N * 144;                 // N*144
    float* as_    = ws + (size_t)2 * N * 144;             // N*6
    float* ad_    = as_ + (size_t)N * 6;                  // N*6
    float* pooled = ad_ + (size_t)N * 6;                  // 144
    int*   off    = (int*)(pooled + 144);                 // N+1
    int*   cur    = off + (N + 1);                        // N (histogram counts / cursors)
    int*   esrc   = cur + N;                              // E

    const int B = 256;
    auto grid = [](long total, int b) { return (int)((total + b - 1) / b); };

    // ---- CSR build (dst shared by both layers) ----
    hipMemsetAsync(cur, 0, (size_t)N * sizeof(int), stream);
    hist_kernel<<<grid(E, B), B, 0, stream>>>(dst, cur, E);
    scan_kernel<<<1, 1024, 0, stream>>>(cur, off, N);
    scatter_kernel<<<grid(E, B), B, 0, stream>>>(src, dst, cur, esrc, E);

    // ---- layer 1 (H=6, F=16, C=96) ----
    gemm4_kernel<11, 96, 2><<<grid((long)(N / 2) * 24, B), B, 0, stream>>>(x, W1, regA, N);
    alpha_kernel<6, 16><<<grid((long)N * 6, B), B, 0, stream>>>(regA, a1s, a1d, as_, ad_, N);
    gather_kernel<6, 16><<<grid((long)N * 24, B), B, 0, stream>>>(off, esrc, as_, ad_, regA, regB, N);

    // ---- layer 2 (H=6, F=24, C=144) ----
    gemm4_kernel<96, 144, 2><<<grid((long)(N / 2) * 36, B), B, 0, stream>>>(regB, W2, regA, N);
    alpha_kernel<6, 24><<<grid((long)N * 6, B), B, 0, stream>>>(regA, a2s, a2d, as_, ad_, N);
    gather_kernel<6, 24><<<grid((long)N * 36, B), B, 0, stream>>>(off, esrc, as_, ad_, regA, regB, N);

    // ---- pool + normalize + linear ----
    hipMemsetAsync(pooled, 0, 144 * sizeof(float), stream);
    pool_kernel<<<288, 256, 0, stream>>>(regB, pooled, N);
    final_kernel<<<1, 64, 0, stream>>>(pooled, Wd, bd, (float*)d_out);
}